// Round 5
// baseline (253.103 us; speedup 1.0000x reference)
//
#include <hip/hip_runtime.h>
#include <math.h>

namespace {
constexpr int B = 2;
constexpr int N = 2048;
constexpr int DIM = 512;
constexpr int H = 8;
constexpr int MEM = 16;
constexpr int J = MEM + N;       // 2064
constexpr int CHUNK = 512;
constexpr int CMAXS = 5;         // ceil(2064/512)
constexpr float S2 = 0.125f * 1.4426950408889634f;  // SCALE * log2(e)
// e-buffer: per b, sum_t (16t+32) j-rows * 16 i * 8 h1 bf16 elems
constexpr size_t EPB = 17170432;        // 134144 * 128
}

typedef __attribute__((ext_vector_type(8))) short short8;
typedef __attribute__((ext_vector_type(2))) float floatx2;
typedef __attribute__((ext_vector_type(4))) float floatx4;
typedef __attribute__((ext_vector_type(4))) unsigned short ushortx4;
typedef __attribute__((ext_vector_type(8))) unsigned short ushortx8;
typedef __attribute__((ext_vector_type(4))) unsigned int uintx4;

__device__ inline unsigned short f2bf(float f) {
    unsigned int u = __float_as_uint(f);
    u += 0x7fffu + ((u >> 16) & 1u);   // RNE
    return (unsigned short)(u >> 16);
}
__device__ inline unsigned int pk2bf(float a, float b) {
    return ((__float_as_uint(a) + 0x8000u) >> 16) |
           ((__float_as_uint(b) + 0x8000u) & 0xffff0000u);
}

// ---------------- P0: x fp32 -> bf16 (streamed once) ----------------------
__global__ __launch_bounds__(256)
void x_conv(const float* __restrict__ x, unsigned short* __restrict__ x16)
{
    const size_t base = ((size_t)blockIdx.x * 256 + threadIdx.x) * 8;
    const float4 a = *(const float4*)(x + base);
    const float4 b = *(const float4*)(x + base + 4);
    ushortx8 o = { f2bf(a.x), f2bf(a.y), f2bf(a.z), f2bf(a.w),
                   f2bf(b.x), f2bf(b.y), f2bf(b.z), f2bf(b.w) };
    *(ushortx8*)(x16 + base) = o;
}

// ---------------- P1: W [k][n] fp32 -> WT [n][k] bf16 (4 matrices) --------
__global__ __launch_bounds__(256)
void wt_conv(const float* __restrict__ Wq, const float* __restrict__ Wk,
             const float* __restrict__ Wv, const float* __restrict__ Wo,
             unsigned short* __restrict__ tq, unsigned short* __restrict__ tk,
             unsigned short* __restrict__ tv, unsigned short* __restrict__ to_)
{
    const int z = blockIdx.z;
    const float* __restrict__ W = (z == 0) ? Wq : (z == 1) ? Wk : (z == 2) ? Wv : Wo;
    unsigned short* __restrict__ WT = (z == 0) ? tq : (z == 1) ? tk : (z == 2) ? tv : to_;
    const int k0 = blockIdx.x * 64, n0 = blockIdx.y * 64;

    __shared__ __align__(16) unsigned short tile[64][72];
    const int t = threadIdx.x;
    const int rrow = t >> 4, rcol = (t & 15) * 4;
#pragma unroll
    for (int rr = 0; rr < 4; ++rr) {
        const int row = rrow + rr * 16;
        const float4 v = *(const float4*)(W + (size_t)(k0 + row) * DIM + n0 + rcol);
        tile[rcol + 0][row] = f2bf(v.x);
        tile[rcol + 1][row] = f2bf(v.y);
        tile[rcol + 2][row] = f2bf(v.z);
        tile[rcol + 3][row] = f2bf(v.w);
    }
    __syncthreads();
    const int orow = t >> 2, oseg = (t & 3) * 16;
    *(ushortx8*)(WT + (size_t)(n0 + orow) * DIM + k0 + oseg) =
        *(const ushortx8*)(&tile[orow][oseg]);
    *(ushortx8*)(WT + (size_t)(n0 + orow) * DIM + k0 + oseg + 8) =
        *(const ushortx8*)(&tile[orow][oseg + 8]);
}

// ---------------- K1: QKV projection GEMM (bf16 in, LDS dbuf, bf16 MFMA) --
// K output head-concatenated: kcat[b][j][h0*64+d]  (for the K=512 GEMM)
__global__ __launch_bounds__(256)
void qkv_gemm(const unsigned short* __restrict__ x16, const unsigned short* __restrict__ tq,
              const unsigned short* __restrict__ tk, const unsigned short* __restrict__ tv,
              unsigned short* __restrict__ q16, unsigned short* __restrict__ kcat,
              unsigned short* __restrict__ vt16)
{
    const int which = blockIdx.z;
    const unsigned short* __restrict__ WT = (which == 0) ? tq : (which == 1) ? tk : tv;
    const int t = threadIdx.x;
    const int lane = t & 63, w = t >> 6;
    const int iL = lane & 15, quad = lane >> 4;
    const int mb = blockIdx.x * 64;
    const int n0 = blockIdx.y * 64;

    __shared__ __align__(16) unsigned short As[2][64][32];  // 8 KB
    __shared__ __align__(16) unsigned short Bs[2][64][32];  // 8 KB

    const int r0 = t >> 2, s8 = (t & 3) * 8;

    floatx4 acc[4];
#pragma unroll
    for (int ng = 0; ng < 4; ++ng) acc[ng] = (floatx4){0.f, 0.f, 0.f, 0.f};

    {
        *(ushortx8*)(&As[0][r0][s8]) =
            *(const ushortx8*)(x16 + (size_t)(mb + r0) * DIM + s8);
        *(ushortx8*)(&Bs[0][r0][s8]) =
            *(const ushortx8*)(WT + (size_t)(n0 + r0) * DIM + s8);
    }
    __syncthreads();

#pragma unroll
    for (int it = 0; it < 16; ++it) {
        const int buf = it & 1;
        if (it + 1 < 16) {
            const int k0 = (it + 1) * 32;
            const ushortx8 av = *(const ushortx8*)(x16 + (size_t)(mb + r0) * DIM + k0 + s8);
            const ushortx8 bv = *(const ushortx8*)(WT + (size_t)(n0 + r0) * DIM + k0 + s8);
            *(ushortx8*)(&As[buf ^ 1][r0][s8]) = av;
            *(ushortx8*)(&Bs[buf ^ 1][r0][s8]) = bv;
        }
        const short8 af = *(const short8*)(&As[buf][w * 16 + iL][quad * 8]);
#pragma unroll
        for (int ng = 0; ng < 4; ++ng) {
            const short8 bf = *(const short8*)(&Bs[buf][ng * 16 + iL][quad * 8]);
            acc[ng] = __builtin_amdgcn_mfma_f32_16x16x32_bf16(af, bf, acc[ng], 0, 0, 0);
        }
        __syncthreads();
    }

    const int mbw = mb + w * 16;
    const int h0 = n0 >> 6;
    if (which == 2) {
#pragma unroll
        for (int ng = 0; ng < 4; ++ng) {
            const int d = ng * 16 + iL;
#pragma unroll
            for (int r = 0; r < 4; ++r) {
                const int m = mbw + quad * 4 + r;
                const int bb = m >> 11, ii = m & (N - 1);
                vt16[((size_t)(bb * H + h0) * 64 + d) * J + MEM + ii] = f2bf(acc[ng][r]);
            }
        }
    } else if (which == 1) {
#pragma unroll
        for (int ng = 0; ng < 4; ++ng) {
            const int d = ng * 16 + iL;
#pragma unroll
            for (int r = 0; r < 4; ++r) {
                const int m = mbw + quad * 4 + r;
                const int bb = m >> 11, ii = m & (N - 1);
                kcat[((size_t)bb * J + MEM + ii) * 512 + h0 * 64 + d] = f2bf(acc[ng][r]);
            }
        }
    } else {
#pragma unroll
        for (int ng = 0; ng < 4; ++ng) {
            const int d = ng * 16 + iL;
#pragma unroll
            for (int r = 0; r < 4; ++r) {
                const int m = mbw + quad * 4 + r;
                const int bb = m >> 11, ii = m & (N - 1);
                q16[((size_t)(bb * H + h0) * N + ii) * 64 + d] = f2bf(acc[ng][r]);
            }
        }
    }
}

// ---------------- K1b: mem_k/mem_v into kcat rows / vt16 cols 0..15 -------
__global__ void memkv_copy(const float* __restrict__ mem_k, const float* __restrict__ mem_v,
                           unsigned short* __restrict__ kcat, unsigned short* __restrict__ vt16)
{
    const int idx = blockIdx.x * 256 + threadIdx.x;  // H*MEM*64 = 8192
    if (idx >= H * MEM * 64) return;
    const int h0 = idx >> 10;
    const int rd = idx & 1023;
    const int r = rd >> 6, d = rd & 63;
    const unsigned short kk = f2bf(mem_k[idx]);
    const unsigned short vv = f2bf(mem_v[idx]);
#pragma unroll
    for (int bb = 0; bb < B; ++bb) {
        kcat[((size_t)bb * J + r) * 512 + h0 * 64 + d] = kk;
        vt16[((size_t)(bb * H + h0) * 64 + d) * J + r] = vv;
    }
}

// ---------------- K2a: scores = K=512 GEMM; Q' resident in REGISTERS ------
// No q_s: each wave builds its 16 Q' fragments (2 h1) once from global (L2).
// LDS holds only the double-buffered K tile (32 KB) -> high occupancy.
__global__ __launch_bounds__(256)
void attn_scores(const unsigned short* __restrict__ qb, const unsigned short* __restrict__ kc,
                 const float* __restrict__ prep, float* __restrict__ lbuf,
                 unsigned short* __restrict__ e16)
{
    const int tt = blockIdx.x, c = 4 - blockIdx.y, b = blockIdx.z;
    const int i0 = tt * 16;
    const int jlim = i0 + 32;
    const int jstart = c * CHUNK;
    if (jstart >= jlim) return;
    const int jend = min(jstart + CHUNK, jlim);
    const int nwin = (jend - jstart) >> 4;      // 16-j windows, jend 16-aligned

    __shared__ __align__(16) unsigned short k_s[2][16][512];  // 32 KB

    const int t = threadIdx.x;
    const int lane = t & 63, w = t >> 6;
    const int iL = lane & 15, quad = lane >> 4;
    const int i = i0 + iL;

    const size_t krowbase = (size_t)b * J * 512;   // u16 units

    // async K staging: linear LDS dest, inverse-swizzled global source
    auto STAGE = [&](int buf, int jw0) {
#pragma unroll
        for (int rr = 0; rr < 4; ++rr) {
            const int row = rr * 4 + w;            // wave-uniform row
            const int j = jw0 + row;
            const char* src = (const char*)(kc + krowbase + (size_t)j * 512);
            const int soff = (lane * 16) ^ ((j & 7) << 4);   // byte swizzle (bijective/row)
            __builtin_amdgcn_global_load_lds(
                (const __attribute__((address_space(1))) unsigned int*)(src + soff),
                (__attribute__((address_space(3))) unsigned int*)(&k_s[buf][row][0]),
                16, 0, 0);
        }
    };

    STAGE(0, jstart);

    // build this wave's Q' fragments from GLOBAL (q-slice is L2-resident):
    // q'[h1, i, (h0,d)] = pre[h0][h1] * q[h0,i,d], packed bf16
    const int h1a = 2 * w, h1b = 2 * w + 1;
    short8 qfA[16], qfB[16];
#pragma unroll
    for (int ks = 0; ks < 16; ++ks) {
        const int h0 = ks >> 1;
        const float sA = prep[h0 * 8 + h1a];
        const float sB = prep[h0 * 8 + h1b];
        const ushortx8 raw = *(const ushortx8*)(
            qb + ((size_t)(b * H + h0) * N + i0 + iL) * 64 + (ks & 1) * 32 + quad * 8);
        uintx4 ua, ub;
#pragma unroll
        for (int e2 = 0; e2 < 4; ++e2) {
            const float f0 = __uint_as_float((unsigned int)raw[e2 * 2] << 16);
            const float f1 = __uint_as_float((unsigned int)raw[e2 * 2 + 1] << 16);
            ua[e2] = pk2bf(f0 * sA, f1 * sA);
            ub[e2] = pk2bf(f0 * sB, f1 * sB);
        }
        qfA[ks] = __builtin_bit_cast(short8, ua);
        qfB[ks] = __builtin_bit_cast(short8, ub);
    }
    __syncthreads();   // k_s[0] staged (barrier drains vmcnt)

    const float slA = 1.4426950408889634f / (float)(2 << h1a);
    const float slB = 1.4426950408889634f / (float)(2 << h1b);
    const size_t ebase = (size_t)b * EPB + (size_t)(8 * tt * tt + 24 * tt) * 128;
    float l0 = 0.f, l1 = 0.f;

    for (int n = 0; n < nwin; ++n) {
        const int buf = n & 1;
        if (n + 1 < nwin) STAGE(buf ^ 1, jstart + (n + 1) * 16);
        const int jw0 = jstart + n * 16;

        floatx4 a0 = {0.f, 0.f, 0.f, 0.f}, a1 = {0.f, 0.f, 0.f, 0.f};
#pragma unroll
        for (int ks = 0; ks < 16; ++ks) {
            const int off = (ks * 32 + quad * 8) ^ ((iL & 7) << 3);   // u16 units
            const short8 aF = *(const short8*)(&k_s[buf][iL][off]);
            a0 = __builtin_amdgcn_mfma_f32_16x16x32_bf16(aF, qfA[ks], a0, 0, 0, 0);
            a1 = __builtin_amdgcn_mfma_f32_16x16x32_bf16(aF, qfB[ks], a1, 0, 0, 0);
        }

#pragma unroll
        for (int r = 0; r < 4; ++r) {
            const int j = jw0 + quad * 4 + r;
            const int jm = j - MEM;
            const bool vis = jm <= i;
            const float bias = (float)(jm - i);
            const float e0 = vis ? exp2f(fmaf(a0[r], S2, slA * bias)) : 0.f;
            const float e1 = vis ? exp2f(fmaf(a1[r], S2, slB * bias)) : 0.f;
            l0 += e0; l1 += e1;
            *(unsigned int*)(e16 + ebase + ((size_t)j * 16 + iL) * 8 + h1a) = pk2bf(e0, e1);
        }
        __syncthreads();   // staging(buf^1) drained + all reads of buf done
    }

    l0 += __shfl_xor(l0, 16); l0 += __shfl_xor(l0, 32);
    l1 += __shfl_xor(l1, 16); l1 += __shfl_xor(l1, 32);
    if (quad == 0) {
        atomicAdd(lbuf + ((size_t)(b * 128 + tt) * 8 + h1a) * 16 + iL, l0);
        atomicAdd(lbuf + ((size_t)(b * 128 + tt) * 8 + h1b) * 16 + iL, l1);
    }
}

// ---------------- K2b: pv pass — 3-deep e-prefetch, dbuf LDS, PV-MFMA -----
__global__ __launch_bounds__(256)
void attn_pv2(const unsigned short* __restrict__ e16, const unsigned short* __restrict__ vt,
              const float* __restrict__ postp, const float* __restrict__ hsp,
              const float* __restrict__ lbuf, float* __restrict__ ao)
{
    const int tt = blockIdx.x, c = 4 - blockIdx.y, b = blockIdx.z;
    const int i0 = tt * 16;
    const int jlim = i0 + 32;
    const int jstart = c * CHUNK;
    if (jstart >= jlim) return;
    const int jend = min(jstart + CHUNK, jlim);
    const int nw = (jend - jstart + 31) >> 5;   // 32-j windows (<=16)

    __shared__ __align__(16) unsigned short p2s[2][8][16][40];  // 20 KB
    __shared__ __align__(16) float post_s[64];

    const int t = threadIdx.x;
    if (t < 64) post_s[t] = postp[t] * hsp[t & 7];

    const int lane = t & 63, w = t >> 6;
    const int iL = lane & 15, quad = lane >> 4;
    const int dW = w * 16 + iL;          // consumer d
    const int i_p = t & 15;              // producer i
    const int jj = t >> 4;               // producer j-group (0..15)
    const size_t ebase = (size_t)b * EPB + (size_t)(8 * tt * tt + 24 * tt) * 128;
    const unsigned short* __restrict__ ep = e16 + ebase + (size_t)i_p * 8;

    float linv[8];
#pragma unroll
    for (int h1 = 0; h1 < 8; ++h1)
        linv[h1] = 1.0f / lbuf[((size_t)(b * 128 + tt) * 8 + h1) * 16 + i_p];

    floatx4 y[8];
#pragma unroll
    for (int h2 = 0; h2 < 8; ++h2) y[h2] = (floatx4){0.f, 0.f, 0.f, 0.f};

    // 3-deep e prefetch: evA = current, evB = +1, evC = +2 (all static regs)
    ushortx8 evA[2], evB[2], evC[2];
    {
        const int j0c = jstart + jj * 2;
        int ja = min(j0c, jend - 1), jb2 = min(j0c + 1, jend - 1);
        evA[0] = *(const ushortx8*)(ep + (size_t)(ja * 16) * 8);
        evA[1] = *(const ushortx8*)(ep + (size_t)(jb2 * 16) * 8);
        ja = min(j0c + 32, jend - 1); jb2 = min(j0c + 33, jend - 1);
        evB[0] = *(const ushortx8*)(ep + (size_t)(ja * 16) * 8);
        evB[1] = *(const ushortx8*)(ep + (size_t)(jb2 * 16) * 8);
        ja = min(j0c + 64, jend - 1); jb2 = min(j0c + 65, jend - 1);
        evC[0] = *(const ushortx8*)(ep + (size_t)(ja * 16) * 8);
        evC[1] = *(const ushortx8*)(ep + (size_t)(jb2 * 16) * 8);
    }
    __syncthreads();   // post_s ready

    for (int n = 0; n < nw; ++n) {
        const int jw0 = jstart + n * 32;
        const int buf = n & 1;

        int jbv = jw0 + quad * 8;
        if (jbv > J - 8) jbv = J - 8;    // only masked cols; p2s=0 for them
        short8 bF[8];
#pragma unroll
        for (int h2 = 0; h2 < 8; ++h2)
            bF[h2] = *(const short8*)(vt + ((size_t)(b * H + h2) * 64 + dW) * J + jbv);

        ushortx8 evT0, evT1;
        {
            const int wn = (n + 3 < nw) ? n + 3 : nw - 1;
            const int j0n = jstart + wn * 32 + jj * 2;
            const int ja = min(j0n, jend - 1), jb2 = min(j0n + 1, jend - 1);
            evT0 = *(const ushortx8*)(ep + (size_t)(ja * 16) * 8);
            evT1 = *(const ushortx8*)(ep + (size_t)(jb2 * 16) * 8);
        }

        floatx2 p2v[2][4];
#pragma unroll
        for (int s = 0; s < 2; ++s) {
#pragma unroll
            for (int q = 0; q < 4; ++q) p2v[s][q] = (floatx2){0.f, 0.f};
            const int j = jw0 + jj * 2 + s;
            if (j < jend) {
#pragma unroll
                for (int h1 = 0; h1 < 8; ++h1) {
                    const float e = __uint_as_float(
                        (unsigned int)(unsigned short)evA[s][h1] << 16) * linv[h1];
                    const floatx2* po = (const floatx2*)(&post_s[h1 * 8]);
                    p2v[s][0] += e * po[0];
                    p2v[s][1] += e * po[1];
                    p2v[s][2] += e * po[2];
                    p2v[s][3] += e * po[3];
                }
            }
        }
#pragma unroll
        for (int h2 = 0; h2 < 8; ++h2)
            *(unsigned int*)(&p2s[buf][h2][i_p][jj * 2]) =
                pk2bf(p2v[0][h2 >> 1][h2 & 1], p2v[1][h2 >> 1][h2 & 1]);
        __syncthreads();

#pragma unroll
        for (int h2 = 0; h2 < 8; ++h2) {
            const short8 aF = *(const short8*)(&p2s[buf][h2][iL][quad * 8]);
            y[h2] = __builtin_amdgcn_mfma_f32_16x16x32_bf16(aF, bF[h2], y[h2], 0, 0, 0);
        }
        evA[0] = evB[0]; evA[1] = evB[1];
        evB[0] = evC[0]; evB[1] = evC[1];
        evC[0] = evT0;   evC[1] = evT1;
    }

#pragma unroll
    for (int h2 = 0; h2 < 8; ++h2) {
#pragma unroll
        for (int r = 0; r < 4; ++r) {
            const int ii = i0 + quad * 4 + r;
            atomicAdd(ao + ((size_t)b * N + ii) * DIM + h2 * 64 + dW, y[h2][r]);
        }
    }
}

// ---------------- K3: output projection GEMM + bias (LDS dbuf, bf16 MFMA) -
__global__ __launch_bounds__(256)
void out_gemm(const float* __restrict__ ain, const unsigned short* __restrict__ WT,
              const float* __restrict__ bo, float* __restrict__ out)
{
    const int t = threadIdx.x;
    const int lane = t & 63, w = t >> 6;
    const int iL = lane & 15, quad = lane >> 4;
    const int mb = blockIdx.x * 64;
    const int n0 = blockIdx.y * 64;

    __shared__ __align__(16) unsigned short As[2][64][32];
    __shared__ __align__(16) unsigned short Bs[2][64][32];

    const int ar0 = t >> 3, as4 = (t & 7) * 4;
    const int br0 = t >> 2, bs8 = (t & 3) * 8;

    floatx4 acc[4];
#pragma unroll
    for (int ng = 0; ng < 4; ++ng) acc[ng] = (floatx4){0.f, 0.f, 0.f, 0.f};

    {
        const float4 v0 = *(const float4*)(ain + (size_t)(mb + ar0) * DIM + as4);
        const float4 v1 = *(const float4*)(ain + (size_t)(mb + ar0 + 32) * DIM + as4);
        ushortx4 o0 = { f2bf(v0.x), f2bf(v0.y), f2bf(v0.z), f2bf(v0.w) };
        ushortx4 o1 = { f2bf(v1.x), f2bf(v1.y), f2bf(v1.z), f2bf(v1.w) };
        *(ushortx4*)(&As[0][ar0][as4]) = o0;
        *(ushortx4*)(&As[0][ar0 + 32][as4]) = o1;
        *(ushortx8*)(&Bs[0][br0][bs8]) =
            *(const ushortx8*)(WT + (size_t)(n0 + br0) * DIM + bs8);
    }
    __syncthreads();

#pragma unroll
    for (int it = 0; it < 16; ++it) {
        const int buf = it & 1;
        if (it + 1 < 16) {
            const int k0 = (it + 1) * 32;
            const float4 v0 = *(const float4*)(ain + (size_t)(mb + ar0) * DIM + k0 + as4);
            const float4 v1 = *(const float4*)(ain + (size_t)(mb + ar0 + 32) * DIM + k0 + as4);
            const ushortx8 bv =
                *(const ushortx8*)(WT + (size_t)(n0 + br0) * DIM + k0 + bs8);
            ushortx4 o0 = { f2bf(v0.x), f2bf(v0.y), f2bf(v0.z), f2bf(v0.w) };
            ushortx4 o1 = { f2bf(v1.x), f2bf(v1.y), f2bf(v1.z), f2bf(v1.w) };
            *(ushortx4*)(&As[buf ^ 1][ar0][as4]) = o0;
            *(ushortx4*)(&As[buf ^ 1][ar0 + 32][as4]) = o1;
            *(ushortx8*)(&Bs[buf ^ 1][br0][bs8]) = bv;
        }
        const short8 af = *(const short8*)(&As[buf][w * 16 + iL][quad * 8]);
#pragma unroll
        for (int ng = 0; ng < 4; ++ng) {
            const short8 bf = *(const short8*)(&Bs[buf][ng * 16 + iL][quad * 8]);
            acc[ng] = __builtin_amdgcn_mfma_f32_16x16x32_bf16(af, bf, acc[ng], 0, 0, 0);
        }
        __syncthreads();
    }

    const int mbw = mb + w * 16;
#pragma unroll
    for (int ng = 0; ng < 4; ++ng) {
        const int n = n0 + ng * 16 + iL;
        const float bias = bo[n];
#pragma unroll
        for (int r = 0; r < 4; ++r) {
            const int m = mbw + quad * 4 + r;
            out[(size_t)m * DIM + n] = acc[ng][r] + bias;
        }
    }
}

extern "C" void kernel_launch(void* const* d_in, const int* in_sizes, int n_in,
                              void* d_out, int out_size, void* d_ws, size_t ws_size,
                              hipStream_t stream)
{
    (void)in_sizes; (void)n_in; (void)out_size; (void)ws_size;
    const float* x      = (const float*)d_in[0];
    const float* Wq     = (const float*)d_in[1];
    const float* Wk     = (const float*)d_in[2];
    const float* Wv     = (const float*)d_in[3];
    const float* mem_k  = (const float*)d_in[4];
    const float* mem_v  = (const float*)d_in[5];
    const float* pre_p  = (const float*)d_in[6];
    const float* post_p = (const float*)d_in[7];
    const float* hs     = (const float*)d_in[8];
    const float* Wo     = (const float*)d_in[9];
    const float* bo     = (const float*)d_in[10];
    float* out = (float*)d_out;

    constexpr size_t NAO  = (size_t)B * N * DIM;        // 2,097,152 f32
    constexpr size_t NLB  = (size_t)B * 128 * H * 16;   //    32,768 f32
    constexpr size_t NW   = (size_t)DIM * DIM;          //   262,144 u16 each
    constexpr size_t NQ   = (size_t)B * H * N * 64;     // 2,097,152 u16
    constexpr size_t NK   = (size_t)B * J * 512;        // 2,113,536 u16
    constexpr size_t NX   = (size_t)B * N * DIM;        // 2,097,152 u16

    float* ws = (float*)d_ws;
    float* ao   = ws;
    float* lbuf = ao + NAO;
    unsigned short* wtq  = (unsigned short*)(lbuf + NLB);
    unsigned short* wtk  = wtq + NW;
    unsigned short* wtv  = wtk + NW;
    unsigned short* wto  = wtv + NW;
    unsigned short* q16  = wto + NW;
    unsigned short* kcat = q16 + NQ;
    unsigned short* v16  = kcat + NK;
    unsigned short* x16  = v16 + NK;
    unsigned short* e16  = x16 + NX;

    x_conv<<<dim3(1024), 256, 0, stream>>>(x, x16);
    wt_conv<<<dim3(8, 8, 4), 256, 0, stream>>>(Wq, Wk, Wv, Wo, wtq, wtk, wtv, wto);
    qkv_gemm<<<dim3(64, 8, 3), 256, 0, stream>>>(x16, wtq, wtk, wtv, q16, kcat, v16);
    memkv_copy<<<dim3(32), 256, 0, stream>>>(mem_k, mem_v, kcat, v16);
    hipMemsetAsync(ao, 0, (NAO + NLB) * sizeof(float), stream);
    attn_scores<<<dim3(128, CMAXS, B), 256, 0, stream>>>(q16, kcat, pre_p, lbuf, e16);
    attn_pv2<<<dim3(128, CMAXS, B), 256, 0, stream>>>(e16, v16, post_p, hs, lbuf, ao);
    out_gemm<<<dim3(64, 8), 256, 0, stream>>>(ao, wto, bo, out);
}